// Round 14
// baseline (194.773 us; speedup 1.0000x reference)
//
#include <hip/hip_runtime.h>
#include <cstddef>

// CifarNetMem forward, INT8-MFMA path.
// All LUT-quantized values are k/16, k in [-64,64] -> exact i8; i32 MFMA sums are
// EXACT; requant lutq(relu(v)) == clamp((max(S+16*kb,0)+7)>>4, <=64) in pure ints
// => bit-identical to fp32 reference. conv1 fp32 with FIXED fma order (c outer,
// k inner); fc3 logits = (S+16*kb)/256 exact fp32.
// R13->R14: WHOLE conv stack fused into ONE kernel, one block per image, all
// activations in LDS (peak 64.8KB, 2 blocks/CU, 512 blocks). Region lifetimes:
//   X[0,13872) fp32 in | SW/SB[13872,17456) | C1[17456,54448) conv1out 34x34x32
//   C2[0,8192) conv2 slab | C3[54448,64816) 18x18x32 | C4[0,20736) 18x18x64
//   C5[20736,37120) 16x16x64 | C6[54448,60848) 10x10x64 | C7[0,12800) 10x10x128
//   C8[12800,20992) 8x8x128  (each region written only after its space is dead)
// fc_reduce folded into fc_tail (reads i32 partials directly). 7 -> 4 dispatches,
// zero activation global traffic in the conv stack. Same math => bit-identical.

#define B_SZ 512
typedef unsigned int u32;
typedef __attribute__((ext_vector_type(4))) int i32x4;

__device__ __forceinline__ float lutq(float v) {
    float k = ceilf(v * 16.0f - 0.5f);
    k = fminf(64.0f, fmaxf(-64.0f, k));
    return k * 0.0625f;
}
__device__ __forceinline__ int kq(float x) {
    float kf = ceilf(x * 16.0f - 0.5f);
    kf = fminf(64.0f, fmaxf(-64.0f, kf));
    return (int)kf;
}
__device__ __forceinline__ u32 bmax4u(u32 a, u32 b) {
    u32 r = 0;
    #pragma unroll
    for (int j = 0; j < 4; ++j) {
        u32 x = (a >> (8 * j)) & 255u, y = (b >> (8 * j)) & 255u;
        r |= (x > y ? x : y) << (8 * j);
    }
    return r;
}
__device__ __forceinline__ int requant(int s, int kb16) {
    int vv = s + kb16;
    vv = vv > 0 ? vv : 0;
    int kk = (vv + 7) >> 4;
    return kk > 64 ? 64 : kk;
}

// ---------------- weight prep: quantize to i8 + MFMA-fragment order -----------------
__device__ __forceinline__ void prep_conv_frag(const float* __restrict__ w, char* __restrict__ q,
                                               int i, int CI) {
    int NSTEP = (9 * CI + 63) / 64;
    int e = i & 15, t = i >> 4;
    int ln = t & 63, t2 = t >> 6;
    int s = t2 % NSTEP, co_tile = t2 / NSTEP;
    int k = s * 64 + ((ln >> 4) << 4) + e;
    int tap = k / CI, ci = k % CI;
    int co = co_tile * 16 + (ln & 15);
    int val = 0;
    if (tap < 9) val = kq(w[(co * CI + ci) * 9 + tap]);
    q[i] = (char)val;
}
__device__ __forceinline__ void prep_fc_frag(const float* __restrict__ w, char* __restrict__ q,
                                             int i, int K) {
    int S = K >> 6;
    int e = i & 15, t = i >> 4;
    int ln = t & 63, t2 = t >> 6;
    int s = t2 % S, n_tile = t2 / S;
    int n = n_tile * 16 + (ln & 15);
    int k = s * 64 + ((ln >> 4) << 4) + e;
    q[i] = (char)kq(w[(size_t)n * K + k]);
}

__global__ __launch_bounds__(256) void prep_weights(
    const float* __restrict__ w2, const float* __restrict__ w3, const float* __restrict__ w4,
    const float* __restrict__ w5, const float* __restrict__ w6,
    const float* __restrict__ fw1, const float* __restrict__ fw2,
    char* q2, char* q3, char* q4, char* q5, char* q6, char* qf1, char* qf2)
{
    int i = blockIdx.x * 256 + threadIdx.x;
    if (i < 10240)                  { prep_conv_frag(w2, q2, i, 32);  }
    else if ((i -= 10240) < 20480)  { prep_conv_frag(w3, q3, i, 32);  }
    else if ((i -= 20480) < 36864)  { prep_conv_frag(w4, q4, i, 64);  }
    else if ((i -= 36864) < 73728)  { prep_conv_frag(w5, q5, i, 64);  }
    else if ((i -= 73728) < 147456) { prep_conv_frag(w6, q6, i, 128); }
    else if ((i -= 147456) < 1048576){ prep_fc_frag(fw1, qf1, i, 2048); }
    else if ((i -= 1048576) < 65536) { prep_fc_frag(fw2, qf2, i, 512);  }
}

// ---------------- megaconv: conv1..conv6 + pools + fragA, one block per image -------
__global__ __launch_bounds__(256, 2) void megaconv(
    const float* __restrict__ x, const float* __restrict__ w1, const float* __restrict__ b1,
    const char* __restrict__ q2, const float* __restrict__ b2,
    const char* __restrict__ q3, const float* __restrict__ b3,
    const char* __restrict__ q4, const float* __restrict__ b4,
    const char* __restrict__ q5, const float* __restrict__ b5,
    const char* __restrict__ q6, const float* __restrict__ b6,
    char* __restrict__ fc1a)
{
    __shared__ __align__(128) char smem[64816];
    float* X  = (float*)smem;                 // [3][34][34] fp32 halo'd
    float* SW = (float*)(smem + 13872);       // [3][9][32]
    float* SB = (float*)(smem + 17328);       // [32]
    char*  C1 = smem + 17456;                 // 34x34x32 swz (conv1 out)
    char*  C2 = smem;                         // 8x32x32 conv2 slab (over X)
    char*  C3 = smem + 54448;                 // 18x18x32 swz
    char*  C4 = smem;                         // 18x18x64 swz (over X/W/C2)
    char*  C5 = smem + 20736;                 // 16x16x64 plain (over C1)
    char*  C6 = smem + 54448;                 // 10x10x64 swz (over C3)
    char*  C7 = smem;                         // 10x10x128 swz (over C4)
    char*  C8 = smem + 12800;                 // 8x8x128 plain

    const int tid = threadIdx.x;
    const int b   = blockIdx.x;
    const int wv = tid >> 6, ln = tid & 63, l15 = ln & 15, lq = ln >> 4;

    auto dp34 = [](int t) { return (t / 3 - 1) * 34 + (t % 3 - 1); };
    auto dp18 = [](int t) { return (t / 3 - 1) * 18 + (t % 3 - 1); };
    auto dp10 = [](int t) { return (t / 3 - 1) * 10 + (t % 3 - 1); };

    // ---- stage x (halo'd), conv1 weights, zero C1/C3 ----
    for (int i = tid; i < 3468; i += 256) {
        int xx = i % 34, t = i / 34, yy = t % 34, c = t / 34;
        int gy = yy - 1, gx = xx - 1;
        float v = 0.f;
        if ((unsigned)gy < 32u && (unsigned)gx < 32u)
            v = x[(((size_t)b * 3 + c) * 32 + gy) * 32 + gx];
        X[i] = v;
    }
    for (int i = tid; i < 864; i += 256) {
        int o = i % 32, k = (i / 32) % 9, c = i / 288;
        SW[(c * 9 + k) * 32 + o] = lutq(w1[(o * 3 + c) * 9 + k]);
    }
    if (tid < 32) SB[tid] = lutq(b1[tid]);
    for (int i = tid; i < 9248; i += 256) ((u32*)C1)[i] = 0u;
    for (int i = tid; i < 2592; i += 256) ((u32*)C3)[i] = 0u;
    __syncthreads();

    // ---- conv1: fp32, FIXED fma order (c outer, k inner), 4 px/thread ----
    for (int qq = 0; qq < 4; ++qq) {
        int p = qq * 256 + tid;
        int y = p >> 5, xc = p & 31;
        float acc[32];
        #pragma unroll
        for (int o = 0; o < 32; ++o) acc[o] = 0.f;
        #pragma unroll
        for (int c = 0; c < 3; ++c)
            #pragma unroll
            for (int k = 0; k < 9; ++k) {
                float iv = X[(c * 34 + y + k / 3) * 34 + xc + k % 3];
                #pragma unroll
                for (int o = 0; o < 32; ++o) acc[o] = fmaf(iv, SW[(c * 9 + k) * 32 + o], acc[o]);
            }
        int pix = (y + 1) * 34 + xc + 1;
        #pragma unroll
        for (int j = 0; j < 2; ++j) {
            uint4 pk;
            u32* pw = (u32*)&pk;
            #pragma unroll
            for (int h = 0; h < 4; ++h) {
                u32 w = 0;
                #pragma unroll
                for (int e = 0; e < 4; ++e) {
                    float v = fmaxf(acc[j * 16 + h * 4 + e] + SB[j * 16 + h * 4 + e], 0.f);
                    int kk = (int)ceilf(v * 16.0f - 0.5f);
                    kk = kk > 64 ? 64 : kk;
                    w |= ((u32)kk & 255u) << (8 * e);
                }
                pw[h] = w;
            }
            *(uint4*)(C1 + ((pix * 32 + j * 16) ^ ((pix & 7) << 4))) = pk;
        }
    }
    __syncthreads();

    // ---- conv2 + pool1: 4 row-slabs of 8, A from C1 ----
    for (int r0 = 0; r0 < 32; r0 += 8) {
        int ppad2[4];
        #pragma unroll
        for (int mw = 0; mw < 4; ++mw) {
            int p = (wv * 4 + mw) * 16 + l15;
            ppad2[mw] = (r0 + (p >> 5) + 1) * 34 + (p & 31) + 1;
        }
        i32x4 acc[4][2] = {};
        #pragma unroll
        for (int s = 0; s < 5; ++s) {
            i32x4 bf[2];
            #pragma unroll
            for (int nt = 0; nt < 2; ++nt)
                bf[nt] = *(const i32x4*)(q2 + (((nt * 5 + s) << 10) + (ln << 4)));
            int d0 = dp34(2 * s);
            int d1 = (2 * s + 1 < 9) ? dp34(2 * s + 1) : 0;
            int dd = (lq & 2) ? d1 : d0;
            int ci0 = (lq & 1) << 4;
            #pragma unroll
            for (int mw = 0; mw < 4; ++mw) {
                int pix = ppad2[mw] + dd;
                i32x4 af = *(const i32x4*)(C1 + ((pix * 32 + ci0) ^ ((pix & 7) << 4)));
                #pragma unroll
                for (int nt = 0; nt < 2; ++nt)
                    acc[mw][nt] = __builtin_amdgcn_mfma_i32_16x16x64_i8(af, bf[nt], acc[mw][nt], 0, 0, 0);
            }
        }
        #pragma unroll
        for (int nt = 0; nt < 2; ++nt) {
            int kb16 = 16 * kq(b2[nt * 16 + l15]);
            #pragma unroll
            for (int mw = 0; mw < 4; ++mw)
                #pragma unroll
                for (int r = 0; r < 4; ++r) {
                    int p = (wv * 4 + mw) * 16 + lq * 4 + r;
                    C2[p * 32 + nt * 16 + l15] = (char)requant(acc[mw][nt][r], kb16);
                }
        }
        __syncthreads();
        if (tid < 128) {
            int c16 = tid & 1;
            int pp  = tid >> 1;
            int xo = pp & 15, yo = pp >> 4;
            int pb = (2 * yo) * 32 + 2 * xo;
            uint4 v0 = *(const uint4*)(C2 + (pb)      * 32 + c16 * 16);
            uint4 v1 = *(const uint4*)(C2 + (pb + 1)  * 32 + c16 * 16);
            uint4 v2 = *(const uint4*)(C2 + (pb + 32) * 32 + c16 * 16);
            uint4 v3 = *(const uint4*)(C2 + (pb + 33) * 32 + c16 * 16);
            uint4 rr;
            rr.x = bmax4u(bmax4u(v0.x, v1.x), bmax4u(v2.x, v3.x));
            rr.y = bmax4u(bmax4u(v0.y, v1.y), bmax4u(v2.y, v3.y));
            rr.z = bmax4u(bmax4u(v0.z, v1.z), bmax4u(v2.z, v3.z));
            rr.w = bmax4u(bmax4u(v0.w, v1.w), bmax4u(v2.w, v3.w));
            int py = (r0 >> 1) + yo;
            int c3pix = (py + 1) * 18 + xo + 1;
            *(uint4*)(C3 + ((c3pix * 32 + c16 * 16) ^ ((c3pix & 7) << 4))) = rr;
        }
        __syncthreads();
    }

    // ---- zero C4 ----
    for (int i = tid; i < 5184; i += 256) ((u32*)C4)[i] = 0u;
    __syncthreads();

    int ppad16[4];
    #pragma unroll
    for (int mw = 0; mw < 4; ++mw) {
        int p = (wv * 4 + mw) * 16 + l15;
        ppad16[mw] = ((p >> 4) + 1) * 18 + (p & 15) + 1;
    }

    // ---- conv3: C3 -> C4 ----
    {
        i32x4 acc3[4][4] = {};
        #pragma unroll
        for (int s = 0; s < 5; ++s) {
            i32x4 bf[4];
            #pragma unroll
            for (int nt = 0; nt < 4; ++nt)
                bf[nt] = *(const i32x4*)(q3 + (((nt * 5 + s) << 10) + (ln << 4)));
            int d0 = dp18(2 * s);
            int d1 = (2 * s + 1 < 9) ? dp18(2 * s + 1) : 0;
            int dd = (lq & 2) ? d1 : d0;
            int ci0 = (lq & 1) << 4;
            #pragma unroll
            for (int mw = 0; mw < 4; ++mw) {
                int pix = ppad16[mw] + dd;
                i32x4 af = *(const i32x4*)(C3 + ((pix * 32 + ci0) ^ ((pix & 7) << 4)));
                #pragma unroll
                for (int nt = 0; nt < 4; ++nt)
                    acc3[mw][nt] = __builtin_amdgcn_mfma_i32_16x16x64_i8(af, bf[nt], acc3[mw][nt], 0, 0, 0);
            }
        }
        #pragma unroll
        for (int nt = 0; nt < 4; ++nt) {
            int kb16 = 16 * kq(b3[nt * 16 + l15]);
            #pragma unroll
            for (int mw = 0; mw < 4; ++mw)
                #pragma unroll
                for (int r = 0; r < 4; ++r) {
                    int p = (wv * 4 + mw) * 16 + lq * 4 + r;
                    int pix = ((p >> 4) + 1) * 18 + (p & 15) + 1;
                    C4[(pix * 64 + nt * 16 + l15) ^ ((pix & 7) << 4)] =
                        (char)requant(acc3[mw][nt][r], kb16);
                }
        }
    }
    __syncthreads();

    // ---- conv4: C4 -> C5 ; zero C6 ----
    {
        i32x4 acc4[4][4] = {};
        #pragma unroll
        for (int s = 0; s < 9; ++s) {
            i32x4 bf[4];
            #pragma unroll
            for (int nt = 0; nt < 4; ++nt)
                bf[nt] = *(const i32x4*)(q4 + (((nt * 9 + s) << 10) + (ln << 4)));
            int dd = dp18(s);
            int ci0 = lq << 4;
            #pragma unroll
            for (int mw = 0; mw < 4; ++mw) {
                int pix = ppad16[mw] + dd;
                i32x4 af = *(const i32x4*)(C4 + ((pix * 64 + ci0) ^ ((pix & 7) << 4)));
                #pragma unroll
                for (int nt = 0; nt < 4; ++nt)
                    acc4[mw][nt] = __builtin_amdgcn_mfma_i32_16x16x64_i8(af, bf[nt], acc4[mw][nt], 0, 0, 0);
            }
        }
        #pragma unroll
        for (int nt = 0; nt < 4; ++nt) {
            int kb16 = 16 * kq(b4[nt * 16 + l15]);
            #pragma unroll
            for (int mw = 0; mw < 4; ++mw)
                #pragma unroll
                for (int r = 0; r < 4; ++r) {
                    int p = (wv * 4 + mw) * 16 + lq * 4 + r;
                    C5[p * 64 + nt * 16 + l15] = (char)requant(acc4[mw][nt][r], kb16);
                }
        }
    }
    for (int i = tid; i < 1600; i += 256) ((u32*)C6)[i] = 0u;
    __syncthreads();

    // ---- pool2: C5 -> C6 (halo'd swz) ; zero C7 ----
    {
        int c16 = tid & 3;
        int pp  = tid >> 2;
        int xo = pp & 7, yo = pp >> 3;
        int pb = (2 * yo) * 16 + 2 * xo;
        uint4 v0 = *(const uint4*)(C5 + (pb)      * 64 + c16 * 16);
        uint4 v1 = *(const uint4*)(C5 + (pb + 1)  * 64 + c16 * 16);
        uint4 v2 = *(const uint4*)(C5 + (pb + 16) * 64 + c16 * 16);
        uint4 v3 = *(const uint4*)(C5 + (pb + 17) * 64 + c16 * 16);
        uint4 rr;
        rr.x = bmax4u(bmax4u(v0.x, v1.x), bmax4u(v2.x, v3.x));
        rr.y = bmax4u(bmax4u(v0.y, v1.y), bmax4u(v2.y, v3.y));
        rr.z = bmax4u(bmax4u(v0.z, v1.z), bmax4u(v2.z, v3.z));
        rr.w = bmax4u(bmax4u(v0.w, v1.w), bmax4u(v2.w, v3.w));
        int c6pix = (yo + 1) * 10 + xo + 1;
        *(uint4*)(C6 + ((c6pix * 64 + c16 * 16) ^ ((c6pix & 7) << 4))) = rr;
    }
    for (int i = tid; i < 3200; i += 256) ((u32*)C7)[i] = 0u;
    __syncthreads();

    // ---- conv5: C6 -> C7 ----
    const int p0 = wv * 16 + l15;
    const int ppad10 = ((p0 >> 3) + 1) * 10 + (p0 & 7) + 1;
    {
        i32x4 acc5[8] = {};
        #pragma unroll
        for (int s = 0; s < 9; ++s) {
            i32x4 bf[8];
            #pragma unroll
            for (int nt = 0; nt < 8; ++nt)
                bf[nt] = *(const i32x4*)(q5 + (((nt * 9 + s) << 10) + (ln << 4)));
            int dd = dp10(s);
            int ci0 = lq << 4;
            int pix = ppad10 + dd;
            i32x4 af = *(const i32x4*)(C6 + ((pix * 64 + ci0) ^ ((pix & 7) << 4)));
            #pragma unroll
            for (int nt = 0; nt < 8; ++nt)
                acc5[nt] = __builtin_amdgcn_mfma_i32_16x16x64_i8(af, bf[nt], acc5[nt], 0, 0, 0);
        }
        #pragma unroll
        for (int nt = 0; nt < 8; ++nt) {
            int kb16 = 16 * kq(b5[nt * 16 + l15]);
            #pragma unroll
            for (int r = 0; r < 4; ++r) {
                int p = wv * 16 + lq * 4 + r;
                int pix = ((p >> 3) + 1) * 10 + (p & 7) + 1;
                C7[(pix * 128 + nt * 16 + l15) ^ ((pix & 7) << 4)] =
                    (char)requant(acc5[nt][r], kb16);
            }
        }
    }
    __syncthreads();

    // ---- conv6: C7 -> C8 ----
    {
        i32x4 acc6[8] = {};
        #pragma unroll
        for (int s = 0; s < 18; ++s) {
            i32x4 bf[8];
            #pragma unroll
            for (int nt = 0; nt < 8; ++nt)
                bf[nt] = *(const i32x4*)(q6 + (((nt * 18 + s) << 10) + (ln << 4)));
            int dd = dp10(s >> 1);
            int ci0 = ((s & 1) << 6) + (lq << 4);
            int pix = ppad10 + dd;
            i32x4 af = *(const i32x4*)(C7 + ((pix * 128 + ci0) ^ ((pix & 7) << 4)));
            #pragma unroll
            for (int nt = 0; nt < 8; ++nt)
                acc6[nt] = __builtin_amdgcn_mfma_i32_16x16x64_i8(af, bf[nt], acc6[nt], 0, 0, 0);
        }
        #pragma unroll
        for (int nt = 0; nt < 8; ++nt) {
            int kb16 = 16 * kq(b6[nt * 16 + l15]);
            #pragma unroll
            for (int r = 0; r < 4; ++r) {
                int p = wv * 16 + lq * 4 + r;
                C8[p * 128 + nt * 16 + l15] = (char)requant(acc6[nt][r], kb16);
            }
        }
    }
    __syncthreads();

    // ---- pool3 + fc1 fragment-A ----
    if (tid < 128) {
        int c16 = tid & 7;
        int pp  = tid >> 3;
        int xo = pp & 3, yo = pp >> 2;
        int pb = (2 * yo) * 8 + 2 * xo;
        uint4 v0 = *(const uint4*)(C8 + (pb)     * 128 + c16 * 16);
        uint4 v1 = *(const uint4*)(C8 + (pb + 1) * 128 + c16 * 16);
        uint4 v2 = *(const uint4*)(C8 + (pb + 8) * 128 + c16 * 16);
        uint4 v3 = *(const uint4*)(C8 + (pb + 9) * 128 + c16 * 16);
        uint4 rr;
        rr.x = bmax4u(bmax4u(v0.x, v1.x), bmax4u(v2.x, v3.x));
        rr.y = bmax4u(bmax4u(v0.y, v1.y), bmax4u(v2.y, v3.y));
        rr.z = bmax4u(bmax4u(v0.z, v1.z), bmax4u(v2.z, v3.z));
        rr.w = bmax4u(bmax4u(v0.w, v1.w), bmax4u(v2.w, v3.w));
        const char* rv = (const char*)&rr;
        int m = b;
        #pragma unroll
        for (int j = 0; j < 16; ++j) {
            int c = c16 * 16 + j;
            int k = c * 16 + yo * 4 + xo;
            int off = (((m >> 4) * 32 + (k >> 6)) << 10)
                    + ((((k >> 4) & 3) * 16 + (m & 15)) << 4) + (k & 15);
            fc1a[off] = rv[j];
        }
    }
}

// ---------------- fc1 via i8 MFMA, split-K, fragment-ordered A AND B ----------------
template<int N, int K, int SK>
__global__ __launch_bounds__(256) void fc1_splitk(
    const char* __restrict__ xa, const char* __restrict__ wq, int* __restrict__ part)
{
    constexpr int KCH = K / SK;
    constexpr int KS = K / 64;
    const int tid = threadIdx.x, wv = tid >> 6, ln = tid & 63;
    const int l15 = ln & 15, lq = ln >> 4;
    const int m0 = blockIdx.x * 128, n0 = blockIdx.y * 128;
    const int kb = blockIdx.z * KCH;
    const int mq = (wv >> 1) * 4, nq = (wv & 1) * 4;
    i32x4 acc[4][4] = {};
    const char* xr[4];
    const char* wt[4];
    #pragma unroll
    for (int t = 0; t < 4; ++t) {
        xr[t] = xa + (size_t)((m0 >> 4) + mq + t) * KS * 1024 + (ln << 4);
        wt[t] = wq + (size_t)((n0 >> 4) + nq + t) * KS * 1024 + (ln << 4);
    }
    for (int k0 = 0; k0 < KCH; k0 += 64) {
        const int s = (kb + k0) >> 6;
        i32x4 a[4], b[4];
        #pragma unroll
        for (int t = 0; t < 4; ++t) {
            a[t] = *(const i32x4*)(xr[t] + (s << 10));
            b[t] = *(const i32x4*)(wt[t] + (s << 10));
        }
        #pragma unroll
        for (int i = 0; i < 4; ++i)
            #pragma unroll
            for (int j = 0; j < 4; ++j)
                acc[i][j] = __builtin_amdgcn_mfma_i32_16x16x64_i8(a[i], b[j], acc[i][j], 0, 0, 0);
    }
    int* pb = part + (size_t)blockIdx.z * (B_SZ * N);
    #pragma unroll
    for (int j = 0; j < 4; ++j) {
        int n = n0 + (nq + j) * 16 + l15;
        #pragma unroll
        for (int i = 0; i < 4; ++i)
            #pragma unroll
            for (int r = 0; r < 4; ++r) {
                int m = m0 + (mq + i) * 16 + lq * 4 + r;
                pb[(size_t)m * N + n] = acc[i][j][r];
            }
    }
}

// ---------------- fc_tail: reduce fc1 partials + fc2 MFMA + fc3 + softmax -----------
__global__ __launch_bounds__(256) void fc_tail(
    const int* __restrict__ part, const float* __restrict__ fb1,
    const char* __restrict__ qf2, const float* __restrict__ fb2,
    const float* __restrict__ fw3, const float* __restrict__ fb3,
    float* __restrict__ out)
{
    __shared__ __align__(16) char sx[16 * 512];
    __shared__ __align__(16) char sy[16 * 128];
    __shared__ __align__(16) char sw3[10 * 128];
    __shared__ float sb3[10];
    __shared__ int sp[16][16][10];

    const int tid = threadIdx.x;
    const int m0 = blockIdx.x * 16;

    // reduce 16 i32 partial slices + bias + reluq -> i8 sx (swizzled)
    for (int idx = tid; idx < 8192; idx += 256) {
        int r = idx >> 9, c = idx & 511;
        int s = 0;
        #pragma unroll
        for (int k = 0; k < 16; ++k)
            s += part[(size_t)k * (B_SZ * 512) + (size_t)(m0 + r) * 512 + c];
        sx[(r * 512 + c) ^ ((r & 7) << 4)] = (char)requant(s, 16 * kq(fb1[c]));
    }
    for (int i = tid; i < 1280; i += 256) sw3[i] = (char)kq(fw3[i]);
    if (tid < 10) sb3[tid] = lutq(fb3[tid]);
    __syncthreads();

    const int wv = tid >> 6, ln = tid & 63, l15 = ln & 15, lq = ln >> 4;
    const int ntg = wv * 2;
    i32x4 acc[2] = {};
    #pragma unroll
    for (int s = 0; s < 8; ++s) {
        int row = l15;
        i32x4 a = *(const i32x4*)(sx + ((row * 512 + s * 64 + lq * 16) ^ ((row & 7) << 4)));
        #pragma unroll
        for (int nt = 0; nt < 2; ++nt) {
            i32x4 b = *(const i32x4*)(qf2 + (((ntg + nt) * 8 + s) << 10) + (ln << 4));
            acc[nt] = __builtin_amdgcn_mfma_i32_16x16x64_i8(a, b, acc[nt], 0, 0, 0);
        }
    }
    #pragma unroll
    for (int nt = 0; nt < 2; ++nt) {
        int n = (ntg + nt) * 16 + l15;
        int kb16 = 16 * kq(fb2[n]);
        #pragma unroll
        for (int r = 0; r < 4; ++r) {
            int row = lq * 4 + r;
            sy[(row * 128 + n) ^ ((row & 7) << 4)] = (char)requant(acc[nt][r], kb16);
        }
    }
    __syncthreads();

    {
        int r = tid >> 4, g = tid & 15;
        uint2 yv = *(const uint2*)(sy + ((r * 128 + g * 8) ^ ((r & 7) << 4)));
        const char* yb = (const char*)&yv;
        #pragma unroll
        for (int o = 0; o < 10; ++o) {
            uint2 wv2 = *(const uint2*)(sw3 + o * 128 + g * 8);
            const char* wb = (const char*)&wv2;
            int S = 0;
            #pragma unroll
            for (int e = 0; e < 8; ++e) S += (int)yb[e] * (int)wb[e];
            sp[r][g][o] = S;
        }
    }
    __syncthreads();

    if (tid < 16) {
        int r = tid;
        float d[10];
        #pragma unroll
        for (int o = 0; o < 10; ++o) {
            int S = 0;
            #pragma unroll
            for (int g = 0; g < 16; ++g) S += sp[r][g][o];
            d[o] = (float)S * 0.00390625f + sb3[o];   // exact: S/256 + kb/16
        }
        float m = d[0];
        #pragma unroll
        for (int o = 1; o < 10; ++o) m = fmaxf(m, d[o]);
        float e[10];
        float sum = 0.f;
        #pragma unroll
        for (int o = 0; o < 10; ++o) { e[o] = expf(d[o] - m); sum += e[o]; }
        #pragma unroll
        for (int o = 0; o < 10; ++o) out[(size_t)(m0 + r) * 10 + o] = e[o] / sum;
    }
}

extern "C" void kernel_launch(void* const* d_in, const int* in_sizes, int n_in,
                              void* d_out, int out_size, void* d_ws, size_t ws_size,
                              hipStream_t stream)
{
    const float* x   = (const float*)d_in[0];
    const float* w1  = (const float*)d_in[2];
    const float* b1  = (const float*)d_in[3];
    const float* w2  = (const float*)d_in[4];
    const float* b2  = (const float*)d_in[5];
    const float* w3  = (const float*)d_in[6];
    const float* b3  = (const float*)d_in[7];
    const float* w4  = (const float*)d_in[8];
    const float* b4  = (const float*)d_in[9];
    const float* w5  = (const float*)d_in[10];
    const float* b5  = (const float*)d_in[11];
    const float* w6  = (const float*)d_in[12];
    const float* b6  = (const float*)d_in[13];
    const float* fw1 = (const float*)d_in[14];
    const float* fb1 = (const float*)d_in[15];
    const float* fw2 = (const float*)d_in[16];
    const float* fb2 = (const float*)d_in[17];
    const float* fw3 = (const float*)d_in[18];
    const float* fb3 = (const float*)d_in[19];
    float* out = (float*)d_out;

    char* q2  = (char*)d_ws;
    char* q3  = q2 + 10240;
    char* q4  = q3 + 20480;
    char* q5  = q4 + 36864;
    char* q6  = q5 + 73728;
    char* qf1 = q6 + 147456;
    char* qf2 = qf1 + 1048576;
    int*  part = (int*)(qf2 + 65536);          // 16 MiB i32 partials
    char* fc1a = (char*)part + (16u << 20);    // 1 MiB fragment-A

    dim3 blk(256);

    // weight prep: 1,402,880 items
    prep_weights<<<dim3(5480), blk, 0, stream>>>(
        w2, w3, w4, w5, w6, fw1, fw2, q2, q3, q4, q5, q6, qf1, qf2);
    // conv1..conv6 + pools + fragment-A, one block per image
    megaconv<<<dim3(512), blk, 0, stream>>>(
        x, w1, b1, q2, b2, q3, b3, q4, b4, q5, b5, q6, b6, fc1a);
    // fc1: [512,2048]->[512,512] split-K=16 (256 blocks), i32 partials, exact
    fc1_splitk<512, 2048, 16><<<dim3(4, 4, 16), blk, 0, stream>>>(fc1a, qf1, part);
    // reduce + fc2 + fc3 + softmax fused (32 blocks x 16 rows)
    fc_tail<<<dim3(32), blk, 0, stream>>>(part, fb1, qf2, fb2, fw3, fb3, out);
}

// Round 15
// 96.403 us; speedup vs baseline: 2.0204x; 2.0204x over previous
//
#include <hip/hip_runtime.h>
#include <cstddef>

// CifarNetMem forward, INT8-MFMA path.
// All LUT-quantized values are k/16, k in [-64,64] -> exact i8. Products k_a*k_w
// <= 4096, sums <= K*4096 << 2^31 -> i32 MFMA accumulation is EXACT. Requantize:
// lutq(relu(v)) == clamp((max(S + 16*kb, 0) + 7) >> 4, <=64) in pure ints => bit-
// identical to the fp32 reference path. conv1 stays fp32 (raw input) with FIXED
// fma order (c outer, k inner); fc3 logits = (S + 16*kb)/256 exact fp32.
// R14->R15: REVERT to R12 (measured best, 96.7us). R13 (pairwise conv fusion,
// neutral) and R14 (megaconv, 2x regression: per-block weight streaming 108MB
// HBM, MfmaUtil 3-7%, no cross-layer parallelism) both falsified the "fewer
// kernels is better" direction. R12 = merged prep+conv1, conv2+pool fused,
// conv3-6 at 1024-block grids, fc1 split-K=16 + reduce, fused fc_tail.

#define B_SZ 512
typedef unsigned int u32;
typedef __attribute__((ext_vector_type(4))) int i32x4;

__device__ __forceinline__ float lutq(float v) {
    float k = ceilf(v * 16.0f - 0.5f);
    k = fminf(64.0f, fmaxf(-64.0f, k));
    return k * 0.0625f;
}
__device__ __forceinline__ int kq(float x) {
    float kf = ceilf(x * 16.0f - 0.5f);
    kf = fminf(64.0f, fmaxf(-64.0f, kf));
    return (int)kf;
}
__device__ __forceinline__ u32 bmax4u(u32 a, u32 b) {
    u32 r = 0;
    #pragma unroll
    for (int j = 0; j < 4; ++j) {
        u32 x = (a >> (8 * j)) & 255u, y = (b >> (8 * j)) & 255u;
        r |= (x > y ? x : y) << (8 * j);
    }
    return r;
}

// ---------------- weight prep helpers: quantize to i8 + MFMA-fragment order ---------
__device__ __forceinline__ void prep_conv_frag(const float* __restrict__ w, char* __restrict__ q,
                                               int i, int CI) {
    int NSTEP = (9 * CI + 63) / 64;
    int e = i & 15, t = i >> 4;
    int ln = t & 63, t2 = t >> 6;
    int s = t2 % NSTEP, co_tile = t2 / NSTEP;
    int k = s * 64 + ((ln >> 4) << 4) + e;
    int tap = k / CI, ci = k % CI;
    int co = co_tile * 16 + (ln & 15);
    int val = 0;
    if (tap < 9) val = kq(w[(co * CI + ci) * 9 + tap]);
    q[i] = (char)val;
}
__device__ __forceinline__ void prep_fc_frag(const float* __restrict__ w, char* __restrict__ q,
                                             int i, int K) {
    int S = K >> 6;
    int e = i & 15, t = i >> 4;
    int ln = t & 63, t2 = t >> 6;
    int s = t2 % S, n_tile = t2 / S;
    int n = n_tile * 16 + (ln & 15);
    int k = s * 64 + ((ln >> 4) << 4) + e;
    q[i] = (char)kq(w[(size_t)n * K + k]);
}

// ---------------- merged: weight prep (blocks 0..5479) + conv1 (blocks 5480..) ------
// conv1: fp32 (raw input), FIXED fma order (c outer, k inner), all 32 co per thread.
__global__ __launch_bounds__(256) void prep_conv1(
    const float* __restrict__ w2, const float* __restrict__ w3, const float* __restrict__ w4,
    const float* __restrict__ w5, const float* __restrict__ w6,
    const float* __restrict__ fw1, const float* __restrict__ fw2,
    char* q2, char* q3, char* q4, char* q5, char* q6, char* qf1, char* qf2,
    const float* __restrict__ x, const float* __restrict__ w1,
    const float* __restrict__ b1, char* __restrict__ out)
{
    const int tid = threadIdx.x;
    const int bid = blockIdx.x;
    if (bid < 5480) {
        int i = bid * 256 + tid;
        if (i < 10240)                  { prep_conv_frag(w2, q2, i, 32);  }
        else if ((i -= 10240) < 20480)  { prep_conv_frag(w3, q3, i, 32);  }
        else if ((i -= 20480) < 36864)  { prep_conv_frag(w4, q4, i, 64);  }
        else if ((i -= 36864) < 73728)  { prep_conv_frag(w5, q5, i, 64);  }
        else if ((i -= 73728) < 147456) { prep_conv_frag(w6, q6, i, 128); }
        else if ((i -= 147456) < 1048576){ prep_fc_frag(fw1, qf1, i, 2048); }
        else if ((i -= 1048576) < 65536) { prep_fc_frag(fw2, qf2, i, 512);  }
        return;
    }
    __shared__ float s_w[3][9][32];
    __shared__ float s_b[32];
    __shared__ float s_in[3][10][34];
    const int bx  = bid - 5480;
    const int b   = bx >> 2;                  // image
    const int r0  = (bx & 3) * 8;             // row quarter
    for (int i = tid; i < 864; i += 256) {
        int o = i % 32, k = (i / 32) % 9, c = i / 288;
        s_w[c][k][o] = lutq(w1[(o * 3 + c) * 9 + k]);
    }
    if (tid < 32) s_b[tid] = lutq(b1[tid]);
    for (int i = tid; i < 3 * 10 * 34; i += 256) {
        int xx = i % 34, yy = (i / 34) % 10, c = i / 340;
        int gy = r0 + yy - 1, gx = xx - 1;
        float v = 0.f;
        if ((unsigned)gy < 32u && (unsigned)gx < 32u)
            v = x[(((size_t)b * 3 + c) * 32 + gy) * 32 + gx];
        s_in[c][yy][xx] = v;
    }
    __syncthreads();
    const int y = tid >> 5, xx = tid & 31;
    float acc[32];
    #pragma unroll
    for (int o = 0; o < 32; ++o) acc[o] = 0.f;
    #pragma unroll
    for (int c = 0; c < 3; ++c) {
        #pragma unroll
        for (int k = 0; k < 9; ++k) {
            float iv = s_in[c][y + k / 3][xx + k % 3];
            #pragma unroll
            for (int o = 0; o < 32; ++o) acc[o] = fmaf(iv, s_w[c][k][o], acc[o]);
        }
    }
    u32 u[8];
    #pragma unroll
    for (int j = 0; j < 8; ++j) {
        u32 p = 0;
        #pragma unroll
        for (int q = 0; q < 4; ++q) {
            float v = fmaxf(acc[4 * j + q] + s_b[4 * j + q], 0.f);
            int kk = (int)ceilf(v * 16.0f - 0.5f);
            kk = kk > 64 ? 64 : kk;
            p |= ((u32)kk & 255u) << (8 * q);
        }
        u[j] = p;
    }
    const int p = (b << 10) + ((r0 + y) << 5) + xx;
    u32* o4 = (u32*)(out + (size_t)p * 32);
    #pragma unroll
    for (int j = 0; j < 8; ++j) o4[j] = u[j];
}

// ---------------- MFMA implicit-GEMM conv: NHWC i8 in, optional fused pool ----------
// POOL: 0 = plain NHWC; 1 = 2x2-maxpooled NHWC; 2 = 2x2-maxpooled fc1-FRAGMENT-A out.
template<int HW, int CI, int CO, int RS, int NIMG, int NT, int POOL = 0>
__global__ __launch_bounds__(256) void conv_mfma(
    const char* __restrict__ in,   // [B][HW][HW][CI] i8
    const char* __restrict__ wq,   // fragment-ordered i8
    const float* __restrict__ bias,
    char* __restrict__ out)
{
    constexpr int PH  = HW + 2;
    constexpr int PIX = NIMG * (RS + 2) * PH;
    constexpr int M   = NIMG * RS * HW;
    constexpr int MT  = M / 16;
    constexpr int MW  = MT / 4;
    constexpr int NSTEP = (9 * CI + 63) / 64;
    constexpr int SL  = HW / RS;
    constexpr int NC16 = CI / 16;
    constexpr int NTC = NT * 16;

    __shared__ __align__(128) char s_in[PIX * CI];

    const int tid = threadIdx.x;
    const int g   = blockIdx.x;
    const int b0  = (g / SL) * NIMG;
    const int r0  = (g % SL) * RS;
    const int co0 = blockIdx.y * NTC;

    constexpr int TOTC = PIX * NC16;
    for (int i = tid; i < TOTC; i += 256) {
        int c16 = i % NC16;
        int pp  = i / NC16;
        int xx  = pp % PH;
        int rr  = pp / PH;
        int yy  = rr % (RS + 2);
        int img = rr / (RS + 2);
        int gy = r0 + yy - 1, gx = xx - 1;
        uint4 v = {0u, 0u, 0u, 0u};
        if ((unsigned)gy < (unsigned)HW && (unsigned)gx < (unsigned)HW)
            v = *(const uint4*)(in + ((((size_t)(b0 + img) * HW + gy) * HW + gx) * CI + c16 * 16));
        int off = (pp * CI + c16 * 16) ^ ((pp & 7) << 4);
        *(uint4*)(s_in + off) = v;
    }
    __syncthreads();

    const int wv = tid >> 6, ln = tid & 63;
    const int l15 = ln & 15, lq = ln >> 4;

    int ppad[MW];
    #pragma unroll
    for (int mw = 0; mw < MW; ++mw) {
        int p = (wv * MW + mw) * 16 + l15;
        int img = p / (RS * HW);
        int rem = p % (RS * HW);
        int ly = rem / HW, lx = rem % HW;
        ppad[mw] = (img * (RS + 2) + ly + 1) * PH + lx + 1;
    }

    i32x4 acc[MW][NT] = {};

    const char* wtile = wq + ((size_t)blockIdx.y * NT) * NSTEP * 1024 + (ln << 4);
    auto dp = [](int t) { return (t / 3 - 1) * PH + (t % 3 - 1); };

    #pragma unroll
    for (int s = 0; s < NSTEP; ++s) {
        i32x4 bf[NT];
        #pragma unroll
        for (int nt = 0; nt < NT; ++nt)
            bf[nt] = *(const i32x4*)(wtile + ((nt * NSTEP + s) << 10));
        int dd, ci0;
        if constexpr (CI == 32) {
            int d0 = dp(2 * s);
            int d1 = (2 * s + 1 < 9) ? dp(2 * s + 1) : 0;
            dd  = (lq & 2) ? d1 : d0;
            ci0 = (lq & 1) << 4;
        } else if constexpr (CI == 64) {
            dd  = dp(s);
            ci0 = lq << 4;
        } else {
            dd  = dp(s >> 1);
            ci0 = ((s & 1) << 6) + (lq << 4);
        }
        #pragma unroll
        for (int mw = 0; mw < MW; ++mw) {
            int pix = ppad[mw] + dd;
            int off = (pix * CI + ci0) ^ ((pix & 7) << 4);
            i32x4 af = *(const i32x4*)(s_in + off);
            #pragma unroll
            for (int nt = 0; nt < NT; ++nt)
                acc[mw][nt] = __builtin_amdgcn_mfma_i32_16x16x64_i8(af, bf[nt], acc[mw][nt], 0, 0, 0);
        }
    }

    if constexpr (POOL == 0) {
        #pragma unroll
        for (int nt = 0; nt < NT; ++nt) {
            int kb16 = 16 * kq(bias[co0 + nt * 16 + l15]);
            #pragma unroll
            for (int mw = 0; mw < MW; ++mw) {
                #pragma unroll
                for (int r = 0; r < 4; ++r) {
                    int p = (wv * MW + mw) * 16 + lq * 4 + r;
                    int img = p / (RS * HW), rem = p % (RS * HW);
                    int ly = rem / HW, lx = rem % HW;
                    int vv = acc[mw][nt][r] + kb16;
                    vv = vv > 0 ? vv : 0;
                    int kk = (vv + 7) >> 4;
                    kk = kk > 64 ? 64 : kk;
                    out[(((size_t)(b0 + img) * HW + r0 + ly) * HW + lx) * CO + co0 + nt * 16 + l15] = (char)kk;
                }
            }
        }
    } else {
        __syncthreads();
        char* s_out = s_in;
        #pragma unroll
        for (int nt = 0; nt < NT; ++nt) {
            int kb16 = 16 * kq(bias[co0 + nt * 16 + l15]);
            #pragma unroll
            for (int mw = 0; mw < MW; ++mw) {
                #pragma unroll
                for (int r = 0; r < 4; ++r) {
                    int p = (wv * MW + mw) * 16 + lq * 4 + r;
                    int vv = acc[mw][nt][r] + kb16;
                    vv = vv > 0 ? vv : 0;
                    int kk = (vv + 7) >> 4;
                    kk = kk > 64 ? 64 : kk;
                    s_out[p * NTC + nt * 16 + l15] = (char)kk;
                }
            }
        }
        __syncthreads();
        constexpr int PR = RS / 2, PC = HW / 2, HOW = HW / 2;
        constexpr int OCT = NIMG * PR * PC * (NTC / 16);
        for (int idx = tid; idx < OCT; idx += 256) {
            int c16 = idx % (NTC / 16);
            int pp  = idx / (NTC / 16);
            int xo = pp % PC, yo = (pp / PC) % PR, img = pp / (PC * PR);
            int pb = (img * RS + 2 * yo) * HW + 2 * xo;
            uint4 v0 = *(const uint4*)(s_out + (pb)          * NTC + c16 * 16);
            uint4 v1 = *(const uint4*)(s_out + (pb + 1)      * NTC + c16 * 16);
            uint4 v2 = *(const uint4*)(s_out + (pb + HW)     * NTC + c16 * 16);
            uint4 v3 = *(const uint4*)(s_out + (pb + HW + 1) * NTC + c16 * 16);
            uint4 r;
            r.x = bmax4u(bmax4u(v0.x, v1.x), bmax4u(v2.x, v3.x));
            r.y = bmax4u(bmax4u(v0.y, v1.y), bmax4u(v2.y, v3.y));
            r.z = bmax4u(bmax4u(v0.z, v1.z), bmax4u(v2.z, v3.z));
            r.w = bmax4u(bmax4u(v0.w, v1.w), bmax4u(v2.w, v3.w));
            if constexpr (POOL == 1) {
                *(uint4*)(out + ((((size_t)(b0 + img) * HOW + (r0 >> 1) + yo) * HOW + xo) * CO
                                 + co0 + c16 * 16)) = r;
            } else {
                // fc1 fragment-A layout: K=2048, k = c*16 + yo*4 + xo, m = batch row.
                const char* rv = (const char*)&r;
                int m = b0 + img;
                #pragma unroll
                for (int j = 0; j < 16; ++j) {
                    int c = co0 + c16 * 16 + j;
                    int k = c * 16 + yo * 4 + xo;
                    int off = (((m >> 4) * 32 + (k >> 6)) << 10)
                            + ((((k >> 4) & 3) * 16 + (m & 15)) << 4) + (k & 15);
                    out[off] = rv[j];
                }
            }
        }
    }
}

// ---------------- fc1 via i8 MFMA, split-K, fragment-ordered A AND B ----------------
template<int N, int K, int SK>
__global__ __launch_bounds__(256) void fc1_splitk(
    const char* __restrict__ xa, const char* __restrict__ wq, int* __restrict__ part)
{
    constexpr int KCH = K / SK;
    constexpr int KS = K / 64;
    const int tid = threadIdx.x, wv = tid >> 6, ln = tid & 63;
    const int l15 = ln & 15, lq = ln >> 4;
    const int m0 = blockIdx.x * 128, n0 = blockIdx.y * 128;
    const int kb = blockIdx.z * KCH;
    const int mq = (wv >> 1) * 4, nq = (wv & 1) * 4;
    i32x4 acc[4][4] = {};
    const char* xr[4];
    const char* wt[4];
    #pragma unroll
    for (int t = 0; t < 4; ++t) {
        xr[t] = xa + (size_t)((m0 >> 4) + mq + t) * KS * 1024 + (ln << 4);
        wt[t] = wq + (size_t)((n0 >> 4) + nq + t) * KS * 1024 + (ln << 4);
    }
    for (int k0 = 0; k0 < KCH; k0 += 64) {
        const int s = (kb + k0) >> 6;
        i32x4 a[4], b[4];
        #pragma unroll
        for (int t = 0; t < 4; ++t) {
            a[t] = *(const i32x4*)(xr[t] + (s << 10));
            b[t] = *(const i32x4*)(wt[t] + (s << 10));
        }
        #pragma unroll
        for (int i = 0; i < 4; ++i)
            #pragma unroll
            for (int j = 0; j < 4; ++j)
                acc[i][j] = __builtin_amdgcn_mfma_i32_16x16x64_i8(a[i], b[j], acc[i][j], 0, 0, 0);
    }
    int* pb = part + (size_t)blockIdx.z * (B_SZ * N);
    #pragma unroll
    for (int j = 0; j < 4; ++j) {
        int n = n0 + (nq + j) * 16 + l15;
        #pragma unroll
        for (int i = 0; i < 4; ++i)
            #pragma unroll
            for (int r = 0; r < 4; ++r) {
                int m = m0 + (mq + i) * 16 + lq * 4 + r;
                pb[(size_t)m * N + n] = acc[i][j][r];
            }
    }
}

// reduce SK i32 partials + bias + reluq -> i8
template<int N, int SK>
__global__ __launch_bounds__(256) void fc_reduce(
    const int* __restrict__ part, const float* __restrict__ bias, char* __restrict__ out)
{
    int i = blockIdx.x * 256 + threadIdx.x;
    if (i >= B_SZ * N) return;
    int s = 0;
    #pragma unroll
    for (int k = 0; k < SK; ++k) s += part[(size_t)k * (B_SZ * N) + i];
    int vv = s + 16 * kq(bias[i % N]);
    vv = vv > 0 ? vv : 0;
    int kk = (vv + 7) >> 4;
    kk = kk > 64 ? 64 : kk;
    out[i] = (char)kk;
}

// ---------------- fc_tail: fc2 (MFMA) + requant + fc3 (int dot) + softmax -----------
// One block = 16 batch rows. x = fc1out [512][512] i8 row-major.
__global__ __launch_bounds__(256) void fc_tail(
    const char* __restrict__ x, const char* __restrict__ qf2,
    const float* __restrict__ fb2, const float* __restrict__ fw3,
    const float* __restrict__ fb3, float* __restrict__ out)
{
    __shared__ __align__(16) char sx[16 * 512];
    __shared__ __align__(16) char sy[16 * 128];
    __shared__ __align__(16) char sw3[10 * 128];
    __shared__ float sb3[10];
    __shared__ int sp[16][16][10];

    const int tid = threadIdx.x;
    const int m0 = blockIdx.x * 16;

    for (int idx = tid; idx < 512; idx += 256) {
        int r = idx >> 5, c16 = idx & 31;
        uint4 v = *(const uint4*)(x + (size_t)(m0 + r) * 512 + c16 * 16);
        *(uint4*)(sx + ((r * 512 + c16 * 16) ^ ((r & 7) << 4))) = v;
    }
    for (int i = tid; i < 1280; i += 256) sw3[i] = (char)kq(fw3[i]);
    if (tid < 10) sb3[tid] = lutq(fb3[tid]);
    __syncthreads();

    // fc2: M=16, N=128, K=512. wave wv -> n-tiles wv*2, wv*2+1.
    const int wv = tid >> 6, ln = tid & 63, l15 = ln & 15, lq = ln >> 4;
    const int ntg = wv * 2;
    i32x4 acc[2] = {};
    #pragma unroll
    for (int s = 0; s < 8; ++s) {
        int row = l15;
        i32x4 a = *(const i32x4*)(sx + ((row * 512 + s * 64 + lq * 16) ^ ((row & 7) << 4)));
        #pragma unroll
        for (int nt = 0; nt < 2; ++nt) {
            i32x4 b = *(const i32x4*)(qf2 + (((ntg + nt) * 8 + s) << 10) + (ln << 4));
            acc[nt] = __builtin_amdgcn_mfma_i32_16x16x64_i8(a, b, acc[nt], 0, 0, 0);
        }
    }
    #pragma unroll
    for (int nt = 0; nt < 2; ++nt) {
        int n = (ntg + nt) * 16 + l15;
        int kb16 = 16 * kq(fb2[n]);
        #pragma unroll
        for (int r = 0; r < 4; ++r) {
            int row = lq * 4 + r;
            int vv = acc[nt][r] + kb16;
            vv = vv > 0 ? vv : 0;
            int kk = (vv + 7) >> 4;
            kk = kk > 64 ? 64 : kk;
            sy[(row * 128 + n) ^ ((row & 7) << 4)] = (char)kk;
        }
    }
    __syncthreads();

    // fc3 partial dots: thread (r, g): k = g*8 .. g*8+7 for all 10 outputs
    {
        int r = tid >> 4, g = tid & 15;
        uint2 yv = *(const uint2*)(sy + ((r * 128 + g * 8) ^ ((r & 7) << 4)));
        const char* yb = (const char*)&yv;
        #pragma unroll
        for (int o = 0; o < 10; ++o) {
            uint2 wv2 = *(const uint2*)(sw3 + o * 128 + g * 8);
            const char* wb = (const char*)&wv2;
            int S = 0;
            #pragma unroll
            for (int e = 0; e < 8; ++e) S += (int)yb[e] * (int)wb[e];
            sp[r][g][o] = S;
        }
    }
    __syncthreads();

    if (tid < 16) {
        int r = tid;
        float d[10];
        #pragma unroll
        for (int o = 0; o < 10; ++o) {
            int S = 0;
            #pragma unroll
            for (int g = 0; g < 16; ++g) S += sp[r][g][o];
            d[o] = (float)S * 0.00390625f + sb3[o];   // exact: S/256 + kb/16
        }
        float m = d[0];
        #pragma unroll
        for (int o = 1; o < 10; ++o) m = fmaxf(m, d[o]);
        float e[10];
        float sum = 0.f;
        #pragma unroll
        for (int o = 0; o < 10; ++o) { e[o] = expf(d[o] - m); sum += e[o]; }
        #pragma unroll
        for (int o = 0; o < 10; ++o) out[(size_t)(m0 + r) * 10 + o] = e[o] / sum;
    }
}

extern "C" void kernel_launch(void* const* d_in, const int* in_sizes, int n_in,
                              void* d_out, int out_size, void* d_ws, size_t ws_size,
                              hipStream_t stream)
{
    const float* x   = (const float*)d_in[0];
    const float* w1  = (const float*)d_in[2];
    const float* b1  = (const float*)d_in[3];
    const float* w2  = (const float*)d_in[4];
    const float* b2  = (const float*)d_in[5];
    const float* w3  = (const float*)d_in[6];
    const float* b3  = (const float*)d_in[7];
    const float* w4  = (const float*)d_in[8];
    const float* b4  = (const float*)d_in[9];
    const float* w5  = (const float*)d_in[10];
    const float* b5  = (const float*)d_in[11];
    const float* w6  = (const float*)d_in[12];
    const float* b6  = (const float*)d_in[13];
    const float* fw1 = (const float*)d_in[14];
    const float* fb1 = (const float*)d_in[15];
    const float* fw2 = (const float*)d_in[16];
    const float* fb2 = (const float*)d_in[17];
    const float* fw3 = (const float*)d_in[18];
    const float* fb3 = (const float*)d_in[19];
    float* out = (float*)d_out;

    char* bufA = (char*)d_ws;                 // 16 MiB activations
    char* bufB = bufA + (16u << 20);          // 16 MiB activations
    char* q2  = bufB + (16u << 20);
    char* q3  = q2 + 10240;
    char* q4  = q3 + 20480;
    char* q5  = q4 + 36864;
    char* q6  = q5 + 73728;
    char* qf1 = q6 + 147456;
    char* qf2 = qf1 + 1048576;
    int*  part = (int*)(qf2 + 65536);         // 16 MiB i32 partials
    char* fc1out = (char*)part + (16u << 20); // 256 KiB i8
    char* fc1a   = fc1out + 262144;           // 1 MiB fragment-A for fc1

    dim3 blk(256);

    // prep (blocks 0..5479) + conv1 (blocks 5480..7527)
    prep_conv1<<<dim3(7528), blk, 0, stream>>>(
        w2, w3, w4, w5, w6, fw1, fw2, q2, q3, q4, q5, q6, qf1, qf2,
        x, w1, b1, bufA);
    // conv2 + pool1 -> [512,16,16,32]
    conv_mfma<32, 32, 32, 8, 1, 2, 1><<<dim3(2048, 1), blk, 0, stream>>>(bufA, q2, b2, bufB);
    // conv3 -> [512,16,16,64]  (RS=8 -> 1024 blocks)
    conv_mfma<16, 32, 64, 8, 1, 4, 0><<<dim3(1024, 1), blk, 0, stream>>>(bufB, q3, b3, bufA);
    // conv4 + pool2 -> [512,8,8,64]  (RS=8 -> 1024 blocks)
    conv_mfma<16, 64, 64, 8, 1, 4, 1><<<dim3(1024, 1), blk, 0, stream>>>(bufA, q4, b4, bufB);
    // conv5 -> [512,8,8,128]  (NIMG=1 -> 1024 blocks)
    conv_mfma<8, 64, 128, 8, 1, 4, 0><<<dim3(512, 2), blk, 0, stream>>>(bufB, q5, b5, bufA);
    // conv6 + pool3 -> fc1 fragment-A [512 x 2048]  (NIMG=1 -> 1024 blocks)
    conv_mfma<8, 128, 128, 8, 1, 4, 2><<<dim3(512, 2), blk, 0, stream>>>(bufA, q6, b6, fc1a);
    // fc1: [512,2048]->[512,512] split-K=16 (256 blocks), i32 partials, exact
    fc1_splitk<512, 2048, 16><<<dim3(4, 4, 16), blk, 0, stream>>>(fc1a, qf1, part);
    fc_reduce<512, 16><<<dim3(1024), blk, 0, stream>>>(part, fb1, fc1out);
    // fc2 + fc3 + softmax fused (32 blocks x 16 rows)
    fc_tail<<<dim3(32), blk, 0, stream>>>(fc1out, qf2, fb2, fw3, fb3, out);
}